// Round 1
// baseline (687.171 us; speedup 1.0000x reference)
//
#include <hip/hip_runtime.h>
#include <hip/hip_bf16.h>
#include <math.h>

// align = einsum('bsh,bh->bs', enc, states)/512; w = softmax(align, axis=1);
// ctx = einsum('bsh,bs->bh', enc, w).  B=32, S=8192, H=512, fp32.
// enc = 512 MiB > L3 -> single fused streaming pass (online softmax), partials
// combined in a parallel second kernel.
//
// This round: pass1 occupancy 4->6+ waves/SIMD, explicit depth-2 prefetch,
// wave-uniform (scalar-branch) max-rescale; pass2 parallelized 32->256 blocks.

#define BB 32
#define SS 8192
#define HH 512
#define NB 64              // blocks per batch (was 32)
#define WPB 4              // waves per block
#define NP (NB * WPB)      // partials per batch = 256
#define RPW (SS / NP)      // rows per wave = 32
#define WCH 8              // pass2 chunks per batch

__global__ __launch_bounds__(256, 6) void attn_pass1(
    const float* __restrict__ states, const float* __restrict__ enc,
    float* __restrict__ align, float* __restrict__ pm,
    float* __restrict__ pl, float* __restrict__ pC)
{
    const int b     = blockIdx.x >> 6;       // / NB
    const int chunk = blockIdx.x & (NB - 1);
    const int lane  = threadIdx.x & 63;
    const int wv    = threadIdx.x >> 6;
    const int p     = chunk * WPB + wv;      // partial index within batch, 0..255

    // states fragment: lane l owns h in [4l,4l+4) and [256+4l,260+4l)
    const float4* st = (const float4*)(states + (size_t)b * HH);
    const float4 sh0 = st[lane];
    const float4 sh1 = st[lane + 64];

    const float4* rp = (const float4*)(enc + ((size_t)b * SS + (size_t)p * RPW) * HH);
    // row r spans rp[r*128 .. r*128+127]

    float  m = -1e30f, l = 0.0f;
    float4 c0 = make_float4(0.f, 0.f, 0.f, 0.f);
    float4 c1 = make_float4(0.f, 0.f, 0.f, 0.f);
    float  my_a = 0.0f;                      // lane r keeps align of local row r (r < RPW)

    // explicit depth-2 software pipeline: rows r, r+1 resident, r+2 in flight
    float4 e0 = rp[lane],        e1 = rp[lane + 64];
    float4 f0 = rp[128 + lane],  f1 = rp[128 + lane + 64];

    #pragma unroll 4
    for (int r = 0; r < RPW; ++r) {
        const int rn = (r + 2 < RPW) ? (r + 2) : (RPW - 1);   // clamp: redundant tail reload, L1-hit
        const float4* q = rp + (size_t)rn * 128;
        float4 g0 = q[lane];
        float4 g1 = q[lane + 64];

        float d = e0.x*sh0.x + e0.y*sh0.y + e0.z*sh0.z + e0.w*sh0.w
                + e1.x*sh1.x + e1.y*sh1.y + e1.z*sh1.z + e1.w*sh1.w;
        #pragma unroll
        for (int off = 1; off < 64; off <<= 1)
            d += __shfl_xor(d, off, 64);

        float a = d * (1.0f / 512.0f);
        // post-butterfly d is identical in all lanes; make that visible to the
        // compiler so the rescale branch is a scalar (wave-uniform) branch.
        a = __uint_as_float(__builtin_amdgcn_readfirstlane(__float_as_uint(a)));

        my_a = (r == lane) ? a : my_a;

        if (a > m) {                          // new running max: rescale (rare after warmup)
            float sc = __expf(m - a);         // exp(-1e30)=0 handles the first row
            l = fmaf(l, sc, 1.0f);            // pr = exp(a-a) = 1
            c0.x = fmaf(c0.x, sc, e0.x);
            c0.y = fmaf(c0.y, sc, e0.y);
            c0.z = fmaf(c0.z, sc, e0.z);
            c0.w = fmaf(c0.w, sc, e0.w);
            c1.x = fmaf(c1.x, sc, e1.x);
            c1.y = fmaf(c1.y, sc, e1.y);
            c1.z = fmaf(c1.z, sc, e1.z);
            c1.w = fmaf(c1.w, sc, e1.w);
            m = a;
        } else {                              // common path: 1 exp + 9 fma
            float pr = __expf(a - m);
            l += pr;
            c0.x = fmaf(pr, e0.x, c0.x);
            c0.y = fmaf(pr, e0.y, c0.y);
            c0.z = fmaf(pr, e0.z, c0.z);
            c0.w = fmaf(pr, e0.w, c0.w);
            c1.x = fmaf(pr, e1.x, c1.x);
            c1.y = fmaf(pr, e1.y, c1.y);
            c1.z = fmaf(pr, e1.z, c1.z);
            c1.w = fmaf(pr, e1.w, c1.w);
        }

        e0 = f0; e1 = f1;
        f0 = g0; f1 = g1;
    }

    if (lane < RPW)
        align[(size_t)b * SS + (size_t)p * RPW + lane] = my_a;
    if (lane == 0) {
        pm[b * NP + p] = m;
        pl[b * NP + p] = l;
    }
    float4* Cp = (float4*)(pC + (size_t)(b * NP + p) * HH);
    Cp[lane]      = c0;
    Cp[lane + 64] = c1;
}

// grid = BB * WCH = 256 blocks. Each block: redundant M/L reduce over the 256
// partials (cheap), then 1/8 of the context combine (float4) + 1/8 of the
// weights write (float4).
__global__ __launch_bounds__(256) void attn_pass2(
    const float* __restrict__ align, const float* __restrict__ pm,
    const float* __restrict__ pl, const float* __restrict__ pC,
    float* __restrict__ out_ctx, float* __restrict__ out_w)
{
    const int b     = blockIdx.x >> 3;      // / WCH
    const int chunk = blockIdx.x & (WCH - 1);
    const int t     = threadIdx.x;
    const int lane  = t & 63;
    const int wv    = t >> 6;

    __shared__ float  s_w[NP];
    __shared__ float  s_red[8];
    __shared__ float  s_bcast[2];
    __shared__ float4 s_part[256];

    // --- global softmax stats (redundant per block; 256 partials) ---
    float pmv = pm[b * NP + t];             // NP == blockDim.x == 256
    float plv = pl[b * NP + t];

    float mx = pmv;
    #pragma unroll
    for (int off = 1; off < 64; off <<= 1)
        mx = fmaxf(mx, __shfl_xor(mx, off, 64));
    if (lane == 0) s_red[wv] = mx;
    __syncthreads();
    if (t == 0)
        s_bcast[0] = fmaxf(fmaxf(s_red[0], s_red[1]), fmaxf(s_red[2], s_red[3]));
    __syncthreads();
    const float M = s_bcast[0];

    float swv = __expf(pmv - M);
    s_w[t] = swv;
    float Lp = swv * plv;
    #pragma unroll
    for (int off = 1; off < 64; off <<= 1)
        Lp += __shfl_xor(Lp, off, 64);
    if (lane == 0) s_red[wv] = Lp;
    __syncthreads();
    if (t == 0)
        s_bcast[1] = 1.0f / (s_red[0] + s_red[1] + s_red[2] + s_red[3]);
    __syncthreads();
    const float invL = s_bcast[1];

    // --- context combine: this block owns h-range [chunk*64, chunk*64+64) ---
    {
        const int slot = t & 15;            // float4 slot within the 64-col range
        const int pg   = t >> 4;            // 16 p-groups
        const float4* Cb4 = (const float4*)(pC + (size_t)b * NP * HH);
        const int colbase = chunk * 16 + slot;   // float4 column index (of 128)
        float4 acc = make_float4(0.f, 0.f, 0.f, 0.f);
        #pragma unroll 4
        for (int p = pg; p < NP; p += 16) {
            float  w = s_w[p];
            float4 v = Cb4[(size_t)p * 128 + colbase];
            acc.x = fmaf(w, v.x, acc.x);
            acc.y = fmaf(w, v.y, acc.y);
            acc.z = fmaf(w, v.z, acc.z);
            acc.w = fmaf(w, v.w, acc.w);
        }
        s_part[t] = acc;
        __syncthreads();
        if (t < 16) {
            float4 tot = make_float4(0.f, 0.f, 0.f, 0.f);
            #pragma unroll
            for (int g = 0; g < 16; ++g) {
                float4 v = s_part[g * 16 + t];
                tot.x += v.x; tot.y += v.y; tot.z += v.z; tot.w += v.w;
            }
            float4* oc4 = (float4*)(out_ctx + (size_t)b * HH);
            oc4[chunk * 16 + t] = make_float4(tot.x * invL, tot.y * invL,
                                              tot.z * invL, tot.w * invL);
        }
    }

    // --- weights: this block owns s-range [chunk*1024, chunk*1024+1024) ---
    {
        const float4* al4 = (const float4*)(align + (size_t)b * SS + chunk * 1024);
        float4*       ow4 = (float4*)(out_w + (size_t)b * SS + chunk * 1024);
        float4 v = al4[t];                  // 256 threads * 4 = 1024 floats
        ow4[t] = make_float4(__expf(v.x - M) * invL, __expf(v.y - M) * invL,
                             __expf(v.z - M) * invL, __expf(v.w - M) * invL);
    }
}

extern "C" void kernel_launch(void* const* d_in, const int* in_sizes, int n_in,
                              void* d_out, int out_size, void* d_ws, size_t ws_size,
                              hipStream_t stream) {
    const float* states = (const float*)d_in[0];   // (32, 512)
    const float* enc    = (const float*)d_in[1];   // (32, 8192, 512)

    float* out_ctx = (float*)d_out;                    // 32*512
    float* out_w   = (float*)d_out + (size_t)BB * HH;  // 32*8192

    // workspace (floats): align[B*S] | pm[B*NP] | pl[B*NP] | pC[B*NP*H]  (~18 MB)
    float* ws_align = (float*)d_ws;
    float* ws_pm    = ws_align + (size_t)BB * SS;
    float* ws_pl    = ws_pm    + (size_t)BB * NP;
    float* ws_pC    = ws_pl    + (size_t)BB * NP;

    attn_pass1<<<BB * NB, 256, 0, stream>>>(states, enc, ws_align, ws_pm, ws_pl, ws_pC);
    attn_pass2<<<BB * WCH, 256, 0, stream>>>(ws_align, ws_pm, ws_pl, ws_pC, out_ctx, out_w);
}